// Round 1
// baseline (2074.138 us; speedup 1.0000x reference)
//
#include <hip/hip_runtime.h>
#include <cmath>

#define LVL   16
#define FPL   2
#define TSIZE (1u << 19)
#define TMASK (TSIZE - 1u)
#define HID   32
#define PRIME1 2654435761u
#define PRIME2 805459861u

struct Scales { float s[LVL]; };

__device__ __forceinline__ float elu_f(float v) {
    return v > 0.0f ? v : expm1f(v);
}

__global__ __launch_bounds__(256)
void field_fwd_kernel(const float* __restrict__ x,
                      const float* __restrict__ table,
                      const float* __restrict__ W0, const float* __restrict__ b0,
                      const float* __restrict__ W1, const float* __restrict__ b1,
                      const float* __restrict__ Wout, const float* __restrict__ bout,
                      float* __restrict__ out, int n, Scales sc)
{
    int tid = blockIdx.x * blockDim.x + threadIdx.x;
    if (tid >= n) return;

    // xn = (x + 1) / 2  (SCALE = 1.0)
    float xn0 = (x[3*tid+0] + 1.0f) * 0.5f;
    float xn1 = (x[3*tid+1] + 1.0f) * 0.5f;
    float xn2 = (x[3*tid+2] + 1.0f) * 0.5f;

    // Layer-0 accumulators, initialized with bias + coord part of feat (dims 0..2)
    float acc[HID];
#pragma unroll
    for (int j = 0; j < HID; ++j)
        acc[j] = b0[j] + xn0 * W0[0*HID + j] + xn1 * W0[1*HID + j] + xn2 * W0[2*HID + j];

#pragma unroll
    for (int l = 0; l < LVL; ++l) {
        float s = sc.s[l];
        float px = xn0 * s, py = xn1 * s, pz = xn2 * s;
        float fx = floorf(px), fy = floorf(py), fz = floorf(pz);
        float wx = px - fx, wy = py - fy, wz = pz - fz;
        unsigned x0 = (unsigned)fx;
        unsigned y0 = (unsigned)fy;
        unsigned z0 = (unsigned)fz;

        unsigned hy0 = y0 * PRIME1, hy1 = hy0 + PRIME1;
        unsigned hz0 = z0 * PRIME2, hz1 = hz0 + PRIME2;
        unsigned b00 = hy0 ^ hz0, b10 = hy1 ^ hz0, b01 = hy0 ^ hz1, b11 = hy1 ^ hz1;

        const float2* tb = (const float2*)table + (size_t)l * TSIZE;
        float2 g000 = tb[( x0       ^ b00) & TMASK];
        float2 g100 = tb[((x0 + 1u) ^ b00) & TMASK];
        float2 g010 = tb[( x0       ^ b10) & TMASK];
        float2 g110 = tb[((x0 + 1u) ^ b10) & TMASK];
        float2 g001 = tb[( x0       ^ b01) & TMASK];
        float2 g101 = tb[((x0 + 1u) ^ b01) & TMASK];
        float2 g011 = tb[( x0       ^ b11) & TMASK];
        float2 g111 = tb[((x0 + 1u) ^ b11) & TMASK];

        float ux = 1.0f - wx, uy = 1.0f - wy, uz = 1.0f - wz;
        float c00 = uy*uz, c10 = wy*uz, c01 = uy*wz, c11 = wy*wz;

        float f0 = ux * (c00*g000.x + c10*g010.x + c01*g001.x + c11*g011.x)
                 + wx * (c00*g100.x + c10*g110.x + c01*g101.x + c11*g111.x);
        float f1 = ux * (c00*g000.y + c10*g010.y + c01*g001.y + c11*g011.y)
                 + wx * (c00*g100.y + c10*g110.y + c01*g101.y + c11*g111.y);

        // fold features (dims 3+2l, 4+2l) into layer-0 accumulators immediately
        const float* w0r0 = W0 + (3 + 2*l) * HID;
        const float* w0r1 = W0 + (4 + 2*l) * HID;
#pragma unroll
        for (int j = 0; j < HID; ++j)
            acc[j] += f0 * w0r0[j] + f1 * w0r1[j];
    }

    // ELU + layer 1
    float h1v[HID];
#pragma unroll
    for (int j = 0; j < HID; ++j) h1v[j] = elu_f(acc[j]);

    float acc2[HID];
#pragma unroll
    for (int j = 0; j < HID; ++j) acc2[j] = b1[j];
#pragma unroll
    for (int k = 0; k < HID; ++k) {
        float hk = h1v[k];
#pragma unroll
        for (int j = 0; j < HID; ++j) acc2[j] += hk * W1[k*HID + j];
    }

    // ELU + output layer
    float o = bout[0];
#pragma unroll
    for (int k = 0; k < HID; ++k) o += elu_f(acc2[k]) * Wout[k];

    out[tid] = o;
}

extern "C" void kernel_launch(void* const* d_in, const int* in_sizes, int n_in,
                              void* d_out, int out_size, void* d_ws, size_t ws_size,
                              hipStream_t stream)
{
    const float* x    = (const float*)d_in[0];
    const float* tb   = (const float*)d_in[1];
    const float* W0   = (const float*)d_in[2];
    const float* b0   = (const float*)d_in[3];
    const float* W1   = (const float*)d_in[4];
    const float* b1   = (const float*)d_in[5];
    const float* Wout = (const float*)d_in[6];
    const float* bo   = (const float*)d_in[7];
    float* out = (float*)d_out;

    int n = in_sizes[0] / 3;

    // s_l = NMIN * B^l - 1, B = exp(log(512/16)/15); compute in double, cast to f32
    Scales sc;
    double B = exp(log(32.0) / 15.0);
    for (int l = 0; l < LVL; ++l)
        sc.s[l] = (float)(16.0 * pow(B, (double)l) - 1.0);

    int block = 256;
    int grid = (n + block - 1) / block;
    field_fwd_kernel<<<grid, block, 0, stream>>>(x, tb, W0, b0, W1, b1, Wout, bo, out, n, sc);
}